// Round 7
// baseline (582.733 us; speedup 1.0000x reference)
//
#include <hip/hip_runtime.h>
#include <hip/hip_bf16.h>
#include <math.h>

#define B_ 4
#define S_ 1024
#define D_ 1024
#define H_ 16
#define HD_ 64
#define M_ 4096
#define E_ 1024

using bf16 = __hip_bfloat16;
typedef short bf16x8 __attribute__((ext_vector_type(8)));
typedef float f32x4 __attribute__((ext_vector_type(4)));

__device__ __forceinline__ void gl_lds16(const void* g, void* l) {
    __builtin_amdgcn_global_load_lds(
        (__attribute__((address_space(1))) void*)(g),
        (__attribute__((address_space(3))) void*)(l), 16, 0, 0);
}

// XOR-swizzled LDS chunk mapping (BK=32 -> 4 x 16B chunks per row):
//  slot c holds global chunk (row = c>>2, seg = (c&3) ^ ((c>>3)&3)).
//  Fragment read offset for (row, qd): row*32 + (qd ^ ((row>>1)&3))*8 elements.
//  R4 measured: SQ_LDS_BANK_CONFLICT 8.4M -> 0. Keep.

// ---------------- weight transpose: Wt[n][k] = bf16(W[k][n]) ----------------
__global__ __launch_bounds__(256) void transpose_kernel(
    const float* __restrict__ W, bf16* __restrict__ Wt, int K, int N)
{
    __shared__ float tile[32][33];
    int n0 = blockIdx.x * 32, k0 = blockIdx.y * 32;
    int tx = threadIdx.x & 31, ty = threadIdx.x >> 5;
    #pragma unroll
    for (int r = ty; r < 32; r += 8)
        tile[r][tx] = W[(long)(k0 + r) * N + n0 + tx];
    __syncthreads();
    #pragma unroll
    for (int r = ty; r < 32; r += 8)
        Wt[(long)(n0 + r) * K + k0 + tx] = __float2bfloat16(tile[tx][r]);
}

// ---------------- emb @ {gates_W, ln1_lW, ln2_lW} + biases, k-split x4 -------
__global__ __launch_bounds__(256) void embgemm_kernel(
    const float* __restrict__ emb,
    const float* __restrict__ W0, const float* __restrict__ b0,
    const float* __restrict__ W1, const float* __restrict__ b1,
    const float* __restrict__ W2, const float* __restrict__ b2,
    float* __restrict__ G, float* __restrict__ SS, float* __restrict__ SS2)
{
    __shared__ float se[256];
    int b = blockIdx.y;
    int k0 = blockIdx.z * 256;
    if (threadIdx.x < 256) se[threadIdx.x] = emb[b * 1024 + k0 + threadIdx.x];
    __syncthreads();
    int j = blockIdx.x * 256 + threadIdx.x;   // 0..6143
    int which = j >> 11, col = j & 2047;
    const float* W  = which == 0 ? W0 : (which == 1 ? W1 : W2);
    const float* bb = which == 0 ? b0 : (which == 1 ? b1 : b2);
    float acc = (k0 == 0) ? bb[col] : 0.f;
    #pragma unroll 4
    for (int k = 0; k < 256; ++k) acc += se[k] * W[(long)(k0 + k) * 2048 + col];
    float* out = which == 0 ? G : (which == 1 ? SS : SS2);
    atomicAdd(&out[b * 2048 + col], acc);
}

// ---------------- rms_norm(x,w)*(1+ss[:D]) + ss[D:] -> bf16 ----------------
__global__ __launch_bounds__(256) void rmsmod_kernel(
    const float* __restrict__ x, const float* __restrict__ w,
    const float* __restrict__ ss, bf16* __restrict__ out)
{
    int row = blockIdx.x;        // 0..4095  (b*S + s)
    int b = row >> 10;
    const float* xr = x + (long)row * D_;
    float4 v = ((const float4*)xr)[threadIdx.x];
    float ssum = v.x * v.x + v.y * v.y + v.z * v.z + v.w * v.w;
    #pragma unroll
    for (int off = 32; off; off >>= 1) ssum += __shfl_xor(ssum, off);
    __shared__ float red[4];
    if ((threadIdx.x & 63) == 0) red[threadIdx.x >> 6] = ssum;
    __syncthreads();
    float tot = red[0] + red[1] + red[2] + red[3];
    float n = sqrtf(tot) * (1.f / 32.f);    // / sqrt(1024)
    float inv = 1.f / (n + 1e-6f);
    int d0 = threadIdx.x * 4;
    const float* ssb = ss + b * 2048;
    bf16 t[4];
    t[0] = __float2bfloat16(v.x * inv * w[d0 + 0] * (1.f + ssb[d0 + 0]) + ssb[D_ + d0 + 0]);
    t[1] = __float2bfloat16(v.y * inv * w[d0 + 1] * (1.f + ssb[d0 + 1]) + ssb[D_ + d0 + 1]);
    t[2] = __float2bfloat16(v.z * inv * w[d0 + 2] * (1.f + ssb[d0 + 2]) + ssb[D_ + d0 + 2]);
    t[3] = __float2bfloat16(v.w * inv * w[d0 + 3] * (1.f + ssb[d0 + 3]) + ssb[D_ + d0 + 3]);
    *(uint2*)&out[(long)row * D_ + d0] = *(uint2*)t;
}

// ---------------- generic 128x128 bf16 MFMA GEMM (1D grid, L2 group swizzle) ----
__global__ __launch_bounds__(256) void gemm_kernel(
    const bf16* __restrict__ A, const bf16* __restrict__ Bt,
    const float* __restrict__ bias,
    bf16* __restrict__ Cb, float* __restrict__ Cf,
    const float* __restrict__ resid, const float* __restrict__ gates, int gate_off,
    int Mrows, int N, int K, int mode)
{
    __shared__ bf16 sA[128 * 32];
    __shared__ bf16 sB[128 * 32];
    const int tid = threadIdx.x;
    const int wave = tid >> 6, lane = tid & 63;
    const int num_pid_n = N >> 7;
    const int pid = blockIdx.x;
    const int group_size = 8 * num_pid_n;
    const int group_id = pid / group_size;
    const int pid_in = pid - group_id * group_size;
    const int pid_m = group_id * 8 + (pid_in & 7);
    const int pid_n = pid_in >> 3;
    const int m0 = pid_m * 128, n0 = pid_n * 128;
    const int wm = (wave & 1) * 64, wn = (wave >> 1) * 64;
    const int cl = lane & 15, qd = lane >> 4;

    f32x4 acc[4][4] = {};

    const int c0 = wave * 128 + lane, c1 = c0 + 64;
    const int r0 = c0 >> 2, s0 = (c0 & 3) ^ ((c0 >> 3) & 3);
    const int r1 = c1 >> 2, s1 = (c1 & 3) ^ ((c1 >> 3) & 3);
    const bf16* gA0 = A + (long)(m0 + r0) * K + s0 * 8;
    const bf16* gA1 = A + (long)(m0 + r1) * K + s1 * 8;
    const bf16* gB0 = Bt + (long)(n0 + r0) * K + s0 * 8;
    const bf16* gB1 = Bt + (long)(n0 + r1) * K + s1 * 8;
    bf16* lA0 = &sA[wave * 1024];
    bf16* lA1 = &sA[wave * 1024 + 512];
    bf16* lB0 = &sB[wave * 1024];
    bf16* lB1 = &sB[wave * 1024 + 512];

    const int q8s = (qd ^ ((cl >> 1) & 3)) * 8;   // swizzled k-chunk offset

    for (int kc = 0; kc < K; kc += 32) {
        gl_lds16(gA0 + kc, lA0);
        gl_lds16(gA1 + kc, lA1);
        gl_lds16(gB0 + kc, lB0);
        gl_lds16(gB1 + kc, lB1);
        __syncthreads();
        bf16x8 af[4], bfr[4];
        #pragma unroll
        for (int t = 0; t < 4; ++t)
            af[t] = *(const bf16x8*)&sA[(wm + cl + t * 16) * 32 + q8s];
        #pragma unroll
        for (int u = 0; u < 4; ++u)
            bfr[u] = *(const bf16x8*)&sB[(wn + cl + u * 16) * 32 + q8s];
        #pragma unroll
        for (int t = 0; t < 4; ++t)
            #pragma unroll
            for (int u = 0; u < 4; ++u)
                acc[t][u] = __builtin_amdgcn_mfma_f32_16x16x32_bf16(af[t], bfr[u], acc[t][u], 0, 0, 0);
        __syncthreads();
    }

    #pragma unroll
    for (int t = 0; t < 4; ++t) {
        #pragma unroll
        for (int u = 0; u < 4; ++u) {
            int col = n0 + wn + u * 16 + cl;
            float bs = bias[col];
            #pragma unroll
            for (int i = 0; i < 4; ++i) {
                int row = m0 + wm + t * 16 + qd * 4 + i;
                float v = acc[t][u][i] + bs;
                if (mode == 0) {
                    Cb[(long)row * N + col] = __float2bfloat16(v);
                } else {
                    int b = row >> 10;
                    float g = gates[b * 2048 + gate_off + col];
                    Cf[(long)row * N + col] = resid[(long)row * N + col] + g * v;
                }
            }
        }
    }
}

// ---------------- split-K 128x128 GEMM with gated-residual atomic epilogue ----
// R6 post-mortem: big-K GEMMs need >=4 blocks/CU AND the 16-MFMA/wave-iter
// inner loop. Out GEMM (M=4096,N=1024,K=4096): 256 tiles x 4 K-slices = 1024
// blocks, each slice K=1024. Epilogue: atomicAdd(Cf, g*acc + (z==0: resid+g*bias)).
// Cf must be pre-zeroed (hipMemsetAsync on stream).
__global__ __launch_bounds__(256) void gemm_splitk_kernel(
    const bf16* __restrict__ A, const bf16* __restrict__ Bt,
    const float* __restrict__ bias,
    float* __restrict__ Cf,
    const float* __restrict__ resid, const float* __restrict__ gates, int gate_off,
    int N, int Ktot, int KS, int zbits)
{
    __shared__ bf16 sA[128 * 32];
    __shared__ bf16 sB[128 * 32];
    const int tid = threadIdx.x;
    const int wave = tid >> 6, lane = tid & 63;
    const int pid = blockIdx.x;
    const int z = pid & ((1 << zbits) - 1);
    const int tile = pid >> zbits;
    const int num_pid_n = N >> 7;
    const int pid_m = tile / num_pid_n;
    const int pid_n = tile - pid_m * num_pid_n;
    const int m0 = pid_m * 128, n0 = pid_n * 128;
    const int wm = (wave & 1) * 64, wn = (wave >> 1) * 64;
    const int cl = lane & 15, qd = lane >> 4;
    const long kbeg = (long)z * KS;

    f32x4 acc[4][4] = {};

    const int c0 = wave * 128 + lane, c1 = c0 + 64;
    const int r0 = c0 >> 2, s0 = (c0 & 3) ^ ((c0 >> 3) & 3);
    const int r1 = c1 >> 2, s1 = (c1 & 3) ^ ((c1 >> 3) & 3);
    const bf16* gA0 = A + (long)(m0 + r0) * Ktot + kbeg + s0 * 8;
    const bf16* gA1 = A + (long)(m0 + r1) * Ktot + kbeg + s1 * 8;
    const bf16* gB0 = Bt + (long)(n0 + r0) * Ktot + kbeg + s0 * 8;
    const bf16* gB1 = Bt + (long)(n0 + r1) * Ktot + kbeg + s1 * 8;
    bf16* lA0 = &sA[wave * 1024];
    bf16* lA1 = &sA[wave * 1024 + 512];
    bf16* lB0 = &sB[wave * 1024];
    bf16* lB1 = &sB[wave * 1024 + 512];

    const int q8s = (qd ^ ((cl >> 1) & 3)) * 8;

    for (int kc = 0; kc < KS; kc += 32) {
        gl_lds16(gA0 + kc, lA0);
        gl_lds16(gA1 + kc, lA1);
        gl_lds16(gB0 + kc, lB0);
        gl_lds16(gB1 + kc, lB1);
        __syncthreads();
        bf16x8 af[4], bfr[4];
        #pragma unroll
        for (int t = 0; t < 4; ++t)
            af[t] = *(const bf16x8*)&sA[(wm + cl + t * 16) * 32 + q8s];
        #pragma unroll
        for (int u = 0; u < 4; ++u)
            bfr[u] = *(const bf16x8*)&sB[(wn + cl + u * 16) * 32 + q8s];
        #pragma unroll
        for (int t = 0; t < 4; ++t)
            #pragma unroll
            for (int u = 0; u < 4; ++u)
                acc[t][u] = __builtin_amdgcn_mfma_f32_16x16x32_bf16(af[t], bfr[u], acc[t][u], 0, 0, 0);
        __syncthreads();
    }

    #pragma unroll
    for (int t = 0; t < 4; ++t) {
        #pragma unroll
        for (int u = 0; u < 4; ++u) {
            int col = n0 + wn + u * 16 + cl;
            float bs = bias[col];
            #pragma unroll
            for (int i = 0; i < 4; ++i) {
                int row = m0 + wm + t * 16 + qd * 4 + i;
                int b = row >> 10;
                float g = gates[b * 2048 + gate_off + col];
                float add = g * acc[t][u][i];
                if (z == 0) add += resid[(long)row * N + col] + g * bs;
                atomicAdd(&Cf[(long)row * N + col], add);
            }
        }
    }
}

// ---------------- 64x64-tile bf16 MFMA GEMM (proj; R5-proven) ----------------
__global__ __launch_bounds__(256) void gemm64_kernel(
    const bf16* __restrict__ A, const bf16* __restrict__ Bt,
    const float* __restrict__ bias,
    bf16* __restrict__ Cb, float* __restrict__ Cf,
    const float* __restrict__ resid, const float* __restrict__ gates, int gate_off,
    int Mrows, int N, int K, int mode)
{
    __shared__ bf16 sA[64 * 32];
    __shared__ bf16 sB[64 * 32];
    const int tid = threadIdx.x;
    const int wave = tid >> 6, lane = tid & 63;
    const int num_pid_n = N >> 6;
    const int pid = blockIdx.x;
    const int group_size = 8 * num_pid_n;
    const int group_id = pid / group_size;
    const int pid_in = pid - group_id * group_size;
    const int pid_m = group_id * 8 + (pid_in & 7);
    const int pid_n = pid_in >> 3;
    const int m0 = pid_m * 64, n0 = pid_n * 64;
    const int wm = (wave & 1) * 32, wn = (wave >> 1) * 32;
    const int cl = lane & 15, qd = lane >> 4;

    f32x4 acc[2][2] = {};

    const int c = tid;
    const int rr = c >> 2, ss = (c & 3) ^ ((c >> 3) & 3);
    const bf16* gA = A + (long)(m0 + rr) * K + ss * 8;
    const bf16* gB = Bt + (long)(n0 + rr) * K + ss * 8;
    bf16* lA = &sA[wave * 512];
    bf16* lB = &sB[wave * 512];

    const int q8s = (qd ^ ((cl >> 1) & 3)) * 8;

    for (int kc = 0; kc < K; kc += 32) {
        gl_lds16(gA + kc, lA);
        gl_lds16(gB + kc, lB);
        __syncthreads();
        bf16x8 af[2], bfr[2];
        #pragma unroll
        for (int t = 0; t < 2; ++t)
            af[t] = *(const bf16x8*)&sA[(wm + cl + t * 16) * 32 + q8s];
        #pragma unroll
        for (int u = 0; u < 2; ++u)
            bfr[u] = *(const bf16x8*)&sB[(wn + cl + u * 16) * 32 + q8s];
        #pragma unroll
        for (int t = 0; t < 2; ++t)
            #pragma unroll
            for (int u = 0; u < 2; ++u)
                acc[t][u] = __builtin_amdgcn_mfma_f32_16x16x32_bf16(af[t], bfr[u], acc[t][u], 0, 0, 0);
        __syncthreads();
    }

    #pragma unroll
    for (int t = 0; t < 2; ++t) {
        #pragma unroll
        for (int u = 0; u < 2; ++u) {
            int col = n0 + wn + u * 16 + cl;
            float bs = bias[col];
            #pragma unroll
            for (int i = 0; i < 4; ++i) {
                int row = m0 + wm + t * 16 + qd * 4 + i;
                float v = acc[t][u][i] + bs;
                if (mode == 0) {
                    Cb[(long)row * N + col] = __float2bfloat16(v);
                } else {
                    int b = row >> 10;
                    float g = gates[b * 2048 + gate_off + col];
                    Cf[(long)row * N + col] = resid[(long)row * N + col] + g * v;
                }
            }
        }
    }
}

// ---------------- fused MLP GEMM + h1*silu(h2), register-light ----------------
// R5 measured: 101us, 680 TF, VGPR 84, occ 27%. Keep.
__global__ __launch_bounds__(256) void gemm_mlp_kernel(
    const bf16* __restrict__ A, const bf16* __restrict__ Bt,
    const float* __restrict__ bias, bf16* __restrict__ ACT)
{
    __shared__ bf16 sA[128 * 32];
    __shared__ bf16 sB1[64 * 32];
    __shared__ bf16 sB2[64 * 32];
    const int tid = threadIdx.x;
    const int wave = tid >> 6, lane = tid & 63;
    const int num_pid_n = 64;            // 4096/64
    const int pid = blockIdx.x;
    const int group_size = 8 * num_pid_n;
    const int group_id = pid / group_size;
    const int pid_in = pid - group_id * group_size;
    const int pid_m = group_id * 8 + (pid_in & 7);
    const int pid_n = pid_in >> 3;
    const int m0 = pid_m * 128, n0 = pid_n * 64;
    const int wm = (wave & 1) * 64, wn = (wave >> 1) * 32;
    const int cl = lane & 15, qd = lane >> 4;
    const int K = 1024;

    f32x4 acc1[4][2] = {};
    f32x4 acc2[4][2] = {};

    const int c0 = wave * 128 + lane, c1 = c0 + 64;
    const int ra0 = c0 >> 2, sa0 = (c0 & 3) ^ ((c0 >> 3) & 3);
    const int ra1 = c1 >> 2, sa1 = (c1 & 3) ^ ((c1 >> 3) & 3);
    const int rb = tid >> 2, sb = (tid & 3) ^ ((tid >> 3) & 3);
    const bf16* gA0 = A + (long)(m0 + ra0) * K + sa0 * 8;
    const bf16* gA1 = A + (long)(m0 + ra1) * K + sa1 * 8;
    const bf16* gB1 = Bt + (long)(n0 + rb) * K + sb * 8;
    const bf16* gB2 = Bt + (long)(4096 + n0 + rb) * K + sb * 8;
    bf16* lA0 = &sA[wave * 1024];
    bf16* lA1 = &sA[wave * 1024 + 512];
    bf16* lB1 = &sB1[wave * 512];
    bf16* lB2 = &sB2[wave * 512];

    const int q8s = (qd ^ ((cl >> 1) & 3)) * 8;

    for (int kc = 0; kc < K; kc += 32) {
        gl_lds16(gA0 + kc, lA0);
        gl_lds16(gA1 + kc, lA1);
        gl_lds16(gB1 + kc, lB1);
        gl_lds16(gB2 + kc, lB2);
        __syncthreads();
        bf16x8 af[4], b1[2], b2[2];
        #pragma unroll
        for (int t = 0; t < 4; ++t)
            af[t] = *(const bf16x8*)&sA[(wm + cl + t * 16) * 32 + q8s];
        #pragma unroll
        for (int u = 0; u < 2; ++u) {
            b1[u] = *(const bf16x8*)&sB1[(wn + cl + u * 16) * 32 + q8s];
            b2[u] = *(const bf16x8*)&sB2[(wn + cl + u * 16) * 32 + q8s];
        }
        #pragma unroll
        for (int t = 0; t < 4; ++t)
            #pragma unroll
            for (int u = 0; u < 2; ++u) {
                acc1[t][u] = __builtin_amdgcn_mfma_f32_16x16x32_bf16(af[t], b1[u], acc1[t][u], 0, 0, 0);
                acc2[t][u] = __builtin_amdgcn_mfma_f32_16x16x32_bf16(af[t], b2[u], acc2[t][u], 0, 0, 0);
            }
        __syncthreads();
    }

    #pragma unroll
    for (int t = 0; t < 4; ++t) {
        #pragma unroll
        for (int u = 0; u < 2; ++u) {
            int col = n0 + wn + u * 16 + cl;
            float bs1 = bias[col];
            float bs2 = bias[4096 + col];
            #pragma unroll
            for (int i = 0; i < 4; ++i) {
                int row = m0 + wm + t * 16 + qd * 4 + i;
                float h1 = acc1[t][u][i] + bs1;
                float h2 = acc2[t][u][i] + bs2;
                float sg = 1.f / (1.f + __expf(-h2));
                ACT[(long)row * 4096 + col] = __float2bfloat16(h1 * h2 * sg);
            }
        }
    }
}

// ---------------- rope + per-head RMS norm; reformat q,k,v ----------------
__global__ __launch_bounds__(256) void ropenorm_kernel(
    const bf16* __restrict__ qkv, const float* __restrict__ nq_w, const float* __restrict__ nk_w,
    bf16* __restrict__ qh, bf16* __restrict__ kh, bf16* __restrict__ vt)
{
    int gid = blockIdx.x * 4 + (threadIdx.x >> 6);  // (b*S+s)*H + h
    int lane = threadIdx.x & 63;
    int b = gid >> 14, s = (gid >> 4) & (S_ - 1), h = gid & (H_ - 1);
    const long base = (long)(b * S_ + s) * 3072 + h * 64 + lane;
    float qv = __bfloat162float(qkv[base]);
    float kv = __bfloat162float(qkv[base + 1024]);
    float vv = __bfloat162float(qkv[base + 2048]);
    // rope
    int j = lane & 31;
    float inv = exp2f(-(float)j * (13.287712379549449f / 32.f)); // 10000^(-j/32)
    float ang = (float)s * inv;
    float sn, c;
    sincosf(ang, &sn, &c);
    float pq = __shfl_xor(qv, 32);
    float pk = __shfl_xor(kv, 32);
    float rq = (lane < 32) ? -pq : pq;
    float rk = (lane < 32) ? -pk : pk;
    float qr = qv * c + rq * sn;
    float kr = kv * c + rk * sn;
    // rms norm over 64 lanes
    float sq = qr * qr, sk = kr * kr;
    #pragma unroll
    for (int off = 32; off; off >>= 1) { sq += __shfl_xor(sq, off); sk += __shfl_xor(sk, off); }
    float nq = sqrtf(sq) * 0.125f;   // / sqrt(64)
    float nk = sqrtf(sk) * 0.125f;
    float qo = qr / (nq + 1e-6f) * nq_w[lane];
    float ko = kr / (nk + 1e-6f) * nk_w[lane];
    long hb = ((long)(b * H_ + h) * S_ + s) * 64 + lane;
    qh[hb] = __float2bfloat16(qo);
    kh[hb] = __float2bfloat16(ko);
    vt[((long)(b * H_ + h) * 64 + lane) * S_ + s] = __float2bfloat16(vv);
}

// ---------------- fused flash-style attention ----------------
__global__ __launch_bounds__(256) void attn_kernel(
    const bf16* __restrict__ qh, const bf16* __restrict__ kh, const bf16* __restrict__ vt,
    bf16* __restrict__ ao)
{
    const int bh = blockIdx.y;
    const int q0 = blockIdx.x * 64;
    const int tid = threadIdx.x, wave = tid >> 6, lane = tid & 63;
    const int cl = lane & 15, qd = lane >> 4;

    __shared__ bf16 sQ[64 * 72];
    __shared__ bf16 sK[64 * 72];
    __shared__ bf16 sV[64 * 72];
    __shared__ bf16 sP[4][16 * 72];

    {   // stage Q tile (64x64)
        const bf16* Qg = qh + (long)bh * S_ * 64 + (long)q0 * 64;
        int a = tid, b2 = tid + 256;
        *(uint4*)&sQ[(a >> 3) * 72 + (a & 7) * 8]  = *(const uint4*)&Qg[(a >> 3) * 64 + (a & 7) * 8];
        *(uint4*)&sQ[(b2 >> 3) * 72 + (b2 & 7) * 8] = *(const uint4*)&Qg[(b2 >> 3) * 64 + (b2 & 7) * 8];
    }

    float m_i[4], l_i[4];
    f32x4 o_acc[4] = {};
    #pragma unroll
    for (int i = 0; i < 4; ++i) { m_i[i] = -1e30f; l_i[i] = 0.f; }

    const bf16* Kg = kh + (long)bh * S_ * 64;
    const bf16* Vg = vt + (long)bh * 64 * S_;

    for (int kv0 = 0; kv0 < S_; kv0 += 64) {
        __syncthreads();
        {   // stage K tile [kv][d] and V^T tile [d][kv]
            int a = tid, b2 = tid + 256;
            *(uint4*)&sK[(a >> 3) * 72 + (a & 7) * 8]   = *(const uint4*)&Kg[((long)kv0 + (a >> 3)) * 64 + (a & 7) * 8];
            *(uint4*)&sK[(b2 >> 3) * 72 + (b2 & 7) * 8] = *(const uint4*)&Kg[((long)kv0 + (b2 >> 3)) * 64 + (b2 & 7) * 8];
            *(uint4*)&sV[(a >> 3) * 72 + (a & 7) * 8]   = *(const uint4*)&Vg[(long)(a >> 3) * S_ + kv0 + (a & 7) * 8];
            *(uint4*)&sV[(b2 >> 3) * 72 + (b2 & 7) * 8] = *(const uint4*)&Vg[(long)(b2 >> 3) * S_ + kv0 + (b2 & 7) * 8];
        }
        __syncthreads();

        // S = Q_wave (16 x 64) @ K_tile^T  -> 4 col-tiles of 16
        f32x4 sfr[4] = {};
        #pragma unroll
        for (int u = 0; u < 4; ++u) {
            #pragma unroll
            for (int ks = 0; ks < 2; ++ks) {
                bf16x8 aq = *(const bf16x8*)&sQ[(wave * 16 + cl) * 72 + ks * 32 + qd * 8];
                bf16x8 bk = *(const bf16x8*)&sK[(u * 16 + cl) * 72 + ks * 32 + qd * 8];
                sfr[u] = __builtin_amdgcn_mfma_f32_16x16x32_bf16(aq, bk, sfr[u], 0, 0, 0);
            }
        }

        // online softmax (rows = qd*4 + i, cols across the 16 lanes of the quad-group)
        float mnew[4], al[4];
        #pragma unroll
        for (int i = 0; i < 4; ++i) {
            float mx = m_i[i];
            #pragma unroll
            for (int u = 0; u < 4; ++u) {
                float s0 = sfr[u][i] * 0.125f;
                sfr[u][i] = s0;
                mx = fmaxf(mx, s0);
            }
            mx = fmaxf(mx, __shfl_xor(mx, 1));
            mx = fmaxf(mx, __shfl_xor(mx, 2));
            mx = fmaxf(mx, __shfl_xor(mx, 4));
            mx = fmaxf(mx, __shfl_xor(mx, 8));
            mnew[i] = mx;
            al[i] = __expf(m_i[i] - mx);
            m_i[i] = mx;
        }
        #pragma unroll
        for (int i = 0; i < 4; ++i) {
            float sum = 0.f;
            #pragma unroll
            for (int u = 0; u < 4; ++u) {
                float p = __expf(sfr[u][i] - mnew[i]);
                sum += p;
                sP[wave][(qd * 4 + i) * 72 + u * 16 + cl] = __float2bfloat16(p);
            }
            sum += __shfl_xor(sum, 1);
            sum += __shfl_xor(sum, 2);
            sum += __shfl_xor(sum, 4);
            sum += __shfl_xor(sum, 8);
            l_i[i] = l_i[i] * al[i] + sum;
        }
        #pragma unroll
        for (int u = 0; u < 4; ++u)
            #pragma unroll
            for (int i = 0; i < 4; ++i) o_acc[u][i] *= al[i];

        // O += P (16 x 64kv) @ V (64kv x 64d); P read back in A-layout from LDS
        #pragma unroll
        for (int ks = 0; ks < 2; ++ks) {
            bf16x8 ap = *(const bf16x8*)&sP[wave][cl * 72 + ks * 32 + qd * 8];
            #pragma unroll
            for (int u = 0; u < 4; ++u) {
                bf16x8 bv = *(const bf16x8*)&sV[(u * 16 + cl) * 72 + ks * 32 + qd * 8];
                o_acc[u] = __builtin_amdgcn_mfma_f32_16x16x32_bf16(ap, bv, o_acc[u], 0, 0, 0);
            }
        }
    }

    // epilogue: ao[b, s, h*64+d]
    #pragma unroll
    for (int i = 0; i < 4; ++i) {
        float invl = 1.f / l_i[i];
        int row = q0 + wave * 16 + qd * 4 + i;
        #pragma unroll
        for (int u = 0; u < 4; ++u) {
            int d = u * 16 + cl;
            ao[((long)(bh >> 4) * S_ + row) * D_ + (bh & 15) * 64 + d] =
                __float2bfloat16(o_acc[u][i] * invl);
        }
    }
}

extern "C" void kernel_launch(void* const* d_in, const int* in_sizes, int n_in,
                              void* d_out, int out_size, void* d_ws, size_t ws_size,
                              hipStream_t stream) {
    const float* x       = (const float*)d_in[0];
    const float* emb     = (const float*)d_in[1];
    const float* ln1_w   = (const float*)d_in[2];
    const float* ln1_lW  = (const float*)d_in[3];
    const float* ln1_lb  = (const float*)d_in[4];
    const float* ln2_w   = (const float*)d_in[5];
    const float* ln2_lW  = (const float*)d_in[6];
    const float* ln2_lb  = (const float*)d_in[7];
    const float* qkv_W   = (const float*)d_in[8];
    const float* qkv_b   = (const float*)d_in[9];
    const float* proj_W  = (const float*)d_in[10];
    const float* proj_b  = (const float*)d_in[11];
    const float* nq_w    = (const float*)d_in[12];
    const float* nk_w    = (const float*)d_in[13];
    const float* mlp_W   = (const float*)d_in[14];
    const float* mlp_b   = (const float*)d_in[15];
    const float* out_W   = (const float*)d_in[16];
    const float* out_b   = (const float*)d_in[17];
    const float* gates_W = (const float*)d_in[18];
    const float* gates_b = (const float*)d_in[19];
    float* out = (float*)d_out;

    // workspace layout (all offsets 256B aligned)
    char* p = (char*)d_ws;
    if (ws_size < 159481856UL) return;  // loud failure rather than OOB corruption
    bf16* WT_QKV  = (bf16*)p;  p += 6291456;   // [3072][1024]
    bf16* WT_PROJ = (bf16*)p;  p += 2097152;   // [1024][1024]
    bf16* WT_MLP  = (bf16*)p;  p += 16777216;  // [8192][1024]
    bf16* WT_OUT  = (bf16*)p;  p += 8388608;   // [1024][4096]
    float* G      = (float*)p; p += 32768;     // [4][2048]
    float* SSb    = (float*)p; p += 32768;
    float* SS2b   = (float*)p; p += 32768;
    float* X1     = (float*)p; p += 16777216;  // f32 [4096][1024]
    bf16* XN2     = (bf16*)p;  p += 8388608;
    bf16* ACT     = (bf16*)p;  p += 33554432;  // [4096][4096]
    char* REG = p;                              // reused region
    bf16* XN   = (bf16*)(REG);
    bf16* QKV  = (bf16*)(REG + 8388608);       // [4096][3072]
    bf16* QH   = (bf16*)(REG + 33554432);      // [B,H,S,HD]
    bf16* KH   = (bf16*)(REG + 41943040);
    bf16* VT   = (bf16*)(REG + 50331648);      // [B,H,HD,S]
    bf16* AO   = (bf16*)(REG + 58720256);      // [4096][1024]

    dim3 blk(256);
    // zero G/SSb/SS2b (96 KB, embgemm atomics) and d_out (16.8 MB, split-K atomics)
    hipMemsetAsync(G, 0, 98304, stream);
    hipMemsetAsync(out, 0, (size_t)out_size * 4, stream);
    transpose_kernel<<<dim3(96, 32),  blk, 0, stream>>>(qkv_W,  WT_QKV, 1024, 3072);
    transpose_kernel<<<dim3(32, 32),  blk, 0, stream>>>(proj_W, WT_PROJ, 1024, 1024);
    transpose_kernel<<<dim3(256, 32), blk, 0, stream>>>(mlp_W,  WT_MLP, 1024, 8192);
    transpose_kernel<<<dim3(32, 128), blk, 0, stream>>>(out_W,  WT_OUT, 4096, 1024);
    embgemm_kernel<<<dim3(24, 4, 4), blk, 0, stream>>>(emb, gates_W, gates_b, ln1_lW, ln1_lb,
                                                       ln2_lW, ln2_lb, G, SSb, SS2b);
    rmsmod_kernel<<<dim3(4096), blk, 0, stream>>>(x, ln1_w, SSb, XN);
    gemm_kernel<<<dim3(768), blk, 0, stream>>>(XN, WT_QKV, qkv_b, QKV, nullptr,
                                               nullptr, nullptr, 0, 4096, 3072, 1024, 0);
    ropenorm_kernel<<<dim3(16384), blk, 0, stream>>>(QKV, nq_w, nk_w, QH, KH, VT);
    attn_kernel<<<dim3(16, 64), blk, 0, stream>>>(QH, KH, VT, AO);
    gemm64_kernel<<<dim3(1024), blk, 0, stream>>>(AO, WT_PROJ, proj_b, nullptr, X1,
                                                  x, G, 0, 4096, 1024, 1024, 1);
    rmsmod_kernel<<<dim3(4096), blk, 0, stream>>>(X1, ln2_w, SS2b, XN2);
    gemm_mlp_kernel<<<dim3(2048), blk, 0, stream>>>(XN2, WT_MLP, mlp_b, ACT);
    gemm_splitk_kernel<<<dim3(1024), blk, 0, stream>>>(ACT, WT_OUT, out_b, out,
                                                       X1, G, 1024, 1024, 4096, 1024, 2);
}

// Round 8
// 523.886 us; speedup vs baseline: 1.1123x; 1.1123x over previous
//
#include <hip/hip_runtime.h>
#include <hip/hip_bf16.h>
#include <math.h>

#define B_ 4
#define S_ 1024
#define D_ 1024
#define H_ 16
#define HD_ 64
#define M_ 4096
#define E_ 1024

using bf16 = __hip_bfloat16;
typedef short bf16x8 __attribute__((ext_vector_type(8)));
typedef float f32x4 __attribute__((ext_vector_type(4)));

__device__ __forceinline__ void gl_lds16(const void* g, void* l) {
    __builtin_amdgcn_global_load_lds(
        (__attribute__((address_space(1))) void*)(g),
        (__attribute__((address_space(3))) void*)(l), 16, 0, 0);
}

// XOR-swizzled LDS chunk mapping (BK=32 -> 4 x 16B chunks per row):
//  slot c holds global chunk (row = c>>2, seg = (c&3) ^ ((c>>3)&3)).
//  Fragment read offset for (row, qd): row*32 + (qd ^ ((row>>1)&3))*8 elements.
//  R4 measured: SQ_LDS_BANK_CONFLICT 8.4M -> 0. Keep.
// GEMM engine lessons (R4-R7, measured):
//  - 16 MFMA/wave-iter + >=3 blocks/CU  => ~650-680 TF (gemm_kernel, gemm_mlp)
//  - 2 blocks/CU (any tile)             => ~340 TF (gemm_wide, R6: 100us out)
//  - atomicAdd split-K epilogue         => +75us of contention (R7: 126us out)
//  - gemm64 @ 4 blocks/CU               => ~430 TF; best known for N=1024 GEMMs

// ---------------- weight transpose: Wt[n][k] = bf16(W[k][n]) ----------------
__global__ __launch_bounds__(256) void transpose_kernel(
    const float* __restrict__ W, bf16* __restrict__ Wt, int K, int N)
{
    __shared__ float tile[32][33];
    int n0 = blockIdx.x * 32, k0 = blockIdx.y * 32;
    int tx = threadIdx.x & 31, ty = threadIdx.x >> 5;
    #pragma unroll
    for (int r = ty; r < 32; r += 8)
        tile[r][tx] = W[(long)(k0 + r) * N + n0 + tx];
    __syncthreads();
    #pragma unroll
    for (int r = ty; r < 32; r += 8)
        Wt[(long)(n0 + r) * K + k0 + tx] = __float2bfloat16(tile[tx][r]);
}

// ---------------- emb @ {gates_W, ln1_lW, ln2_lW} + biases, k-split x4 -------
// R7 triangulation: worth ~-10us vs the 96-block version. Keep.
__global__ __launch_bounds__(256) void embgemm_kernel(
    const float* __restrict__ emb,
    const float* __restrict__ W0, const float* __restrict__ b0,
    const float* __restrict__ W1, const float* __restrict__ b1,
    const float* __restrict__ W2, const float* __restrict__ b2,
    float* __restrict__ G, float* __restrict__ SS, float* __restrict__ SS2)
{
    __shared__ float se[256];
    int b = blockIdx.y;
    int k0 = blockIdx.z * 256;
    if (threadIdx.x < 256) se[threadIdx.x] = emb[b * 1024 + k0 + threadIdx.x];
    __syncthreads();
    int j = blockIdx.x * 256 + threadIdx.x;   // 0..6143
    int which = j >> 11, col = j & 2047;
    const float* W  = which == 0 ? W0 : (which == 1 ? W1 : W2);
    const float* bb = which == 0 ? b0 : (which == 1 ? b1 : b2);
    float acc = (k0 == 0) ? bb[col] : 0.f;
    #pragma unroll 4
    for (int k = 0; k < 256; ++k) acc += se[k] * W[(long)(k0 + k) * 2048 + col];
    float* out = which == 0 ? G : (which == 1 ? SS : SS2);
    atomicAdd(&out[b * 2048 + col], acc);
}

// ---------------- rms_norm(x,w)*(1+ss[:D]) + ss[D:] -> bf16 ----------------
__global__ __launch_bounds__(256) void rmsmod_kernel(
    const float* __restrict__ x, const float* __restrict__ w,
    const float* __restrict__ ss, bf16* __restrict__ out)
{
    int row = blockIdx.x;        // 0..4095  (b*S + s)
    int b = row >> 10;
    const float* xr = x + (long)row * D_;
    float4 v = ((const float4*)xr)[threadIdx.x];
    float ssum = v.x * v.x + v.y * v.y + v.z * v.z + v.w * v.w;
    #pragma unroll
    for (int off = 32; off; off >>= 1) ssum += __shfl_xor(ssum, off);
    __shared__ float red[4];
    if ((threadIdx.x & 63) == 0) red[threadIdx.x >> 6] = ssum;
    __syncthreads();
    float tot = red[0] + red[1] + red[2] + red[3];
    float n = sqrtf(tot) * (1.f / 32.f);    // / sqrt(1024)
    float inv = 1.f / (n + 1e-6f);
    int d0 = threadIdx.x * 4;
    const float* ssb = ss + b * 2048;
    bf16 t[4];
    t[0] = __float2bfloat16(v.x * inv * w[d0 + 0] * (1.f + ssb[d0 + 0]) + ssb[D_ + d0 + 0]);
    t[1] = __float2bfloat16(v.y * inv * w[d0 + 1] * (1.f + ssb[d0 + 1]) + ssb[D_ + d0 + 1]);
    t[2] = __float2bfloat16(v.z * inv * w[d0 + 2] * (1.f + ssb[d0 + 2]) + ssb[D_ + d0 + 2]);
    t[3] = __float2bfloat16(v.w * inv * w[d0 + 3] * (1.f + ssb[d0 + 3]) + ssb[D_ + d0 + 3]);
    *(uint2*)&out[(long)row * D_ + d0] = *(uint2*)t;
}

// ---------------- generic 128x128 bf16 MFMA GEMM (1D grid, L2 group swizzle) ----
__global__ __launch_bounds__(256) void gemm_kernel(
    const bf16* __restrict__ A, const bf16* __restrict__ Bt,
    const float* __restrict__ bias,
    bf16* __restrict__ Cb, float* __restrict__ Cf,
    const float* __restrict__ resid, const float* __restrict__ gates, int gate_off,
    int Mrows, int N, int K, int mode)
{
    __shared__ bf16 sA[128 * 32];
    __shared__ bf16 sB[128 * 32];
    const int tid = threadIdx.x;
    const int wave = tid >> 6, lane = tid & 63;
    const int num_pid_n = N >> 7;
    const int pid = blockIdx.x;
    const int group_size = 8 * num_pid_n;
    const int group_id = pid / group_size;
    const int pid_in = pid - group_id * group_size;
    const int pid_m = group_id * 8 + (pid_in & 7);
    const int pid_n = pid_in >> 3;
    const int m0 = pid_m * 128, n0 = pid_n * 128;
    const int wm = (wave & 1) * 64, wn = (wave >> 1) * 64;
    const int cl = lane & 15, qd = lane >> 4;

    f32x4 acc[4][4] = {};

    const int c0 = wave * 128 + lane, c1 = c0 + 64;
    const int r0 = c0 >> 2, s0 = (c0 & 3) ^ ((c0 >> 3) & 3);
    const int r1 = c1 >> 2, s1 = (c1 & 3) ^ ((c1 >> 3) & 3);
    const bf16* gA0 = A + (long)(m0 + r0) * K + s0 * 8;
    const bf16* gA1 = A + (long)(m0 + r1) * K + s1 * 8;
    const bf16* gB0 = Bt + (long)(n0 + r0) * K + s0 * 8;
    const bf16* gB1 = Bt + (long)(n0 + r1) * K + s1 * 8;
    bf16* lA0 = &sA[wave * 1024];
    bf16* lA1 = &sA[wave * 1024 + 512];
    bf16* lB0 = &sB[wave * 1024];
    bf16* lB1 = &sB[wave * 1024 + 512];

    const int q8s = (qd ^ ((cl >> 1) & 3)) * 8;   // swizzled k-chunk offset

    for (int kc = 0; kc < K; kc += 32) {
        gl_lds16(gA0 + kc, lA0);
        gl_lds16(gA1 + kc, lA1);
        gl_lds16(gB0 + kc, lB0);
        gl_lds16(gB1 + kc, lB1);
        __syncthreads();
        bf16x8 af[4], bfr[4];
        #pragma unroll
        for (int t = 0; t < 4; ++t)
            af[t] = *(const bf16x8*)&sA[(wm + cl + t * 16) * 32 + q8s];
        #pragma unroll
        for (int u = 0; u < 4; ++u)
            bfr[u] = *(const bf16x8*)&sB[(wn + cl + u * 16) * 32 + q8s];
        #pragma unroll
        for (int t = 0; t < 4; ++t)
            #pragma unroll
            for (int u = 0; u < 4; ++u)
                acc[t][u] = __builtin_amdgcn_mfma_f32_16x16x32_bf16(af[t], bfr[u], acc[t][u], 0, 0, 0);
        __syncthreads();
    }

    #pragma unroll
    for (int t = 0; t < 4; ++t) {
        #pragma unroll
        for (int u = 0; u < 4; ++u) {
            int col = n0 + wn + u * 16 + cl;
            float bs = bias[col];
            #pragma unroll
            for (int i = 0; i < 4; ++i) {
                int row = m0 + wm + t * 16 + qd * 4 + i;
                float v = acc[t][u][i] + bs;
                if (mode == 0) {
                    Cb[(long)row * N + col] = __float2bfloat16(v);
                } else {
                    int b = row >> 10;
                    float g = gates[b * 2048 + gate_off + col];
                    Cf[(long)row * N + col] = resid[(long)row * N + col] + g * v;
                }
            }
        }
    }
}

// ---------------- 64x64-tile bf16 MFMA GEMM (proj/out; R5-proven best) --------
__global__ __launch_bounds__(256) void gemm64_kernel(
    const bf16* __restrict__ A, const bf16* __restrict__ Bt,
    const float* __restrict__ bias,
    bf16* __restrict__ Cb, float* __restrict__ Cf,
    const float* __restrict__ resid, const float* __restrict__ gates, int gate_off,
    int Mrows, int N, int K, int mode)
{
    __shared__ bf16 sA[64 * 32];
    __shared__ bf16 sB[64 * 32];
    const int tid = threadIdx.x;
    const int wave = tid >> 6, lane = tid & 63;
    const int num_pid_n = N >> 6;
    const int pid = blockIdx.x;
    const int group_size = 8 * num_pid_n;
    const int group_id = pid / group_size;
    const int pid_in = pid - group_id * group_size;
    const int pid_m = group_id * 8 + (pid_in & 7);
    const int pid_n = pid_in >> 3;
    const int m0 = pid_m * 64, n0 = pid_n * 64;
    const int wm = (wave & 1) * 32, wn = (wave >> 1) * 32;
    const int cl = lane & 15, qd = lane >> 4;

    f32x4 acc[2][2] = {};

    const int c = tid;
    const int rr = c >> 2, ss = (c & 3) ^ ((c >> 3) & 3);
    const bf16* gA = A + (long)(m0 + rr) * K + ss * 8;
    const bf16* gB = Bt + (long)(n0 + rr) * K + ss * 8;
    bf16* lA = &sA[wave * 512];
    bf16* lB = &sB[wave * 512];

    const int q8s = (qd ^ ((cl >> 1) & 3)) * 8;

    for (int kc = 0; kc < K; kc += 32) {
        gl_lds16(gA + kc, lA);
        gl_lds16(gB + kc, lB);
        __syncthreads();
        bf16x8 af[2], bfr[2];
        #pragma unroll
        for (int t = 0; t < 2; ++t)
            af[t] = *(const bf16x8*)&sA[(wm + cl + t * 16) * 32 + q8s];
        #pragma unroll
        for (int u = 0; u < 2; ++u)
            bfr[u] = *(const bf16x8*)&sB[(wn + cl + u * 16) * 32 + q8s];
        #pragma unroll
        for (int t = 0; t < 2; ++t)
            #pragma unroll
            for (int u = 0; u < 2; ++u)
                acc[t][u] = __builtin_amdgcn_mfma_f32_16x16x32_bf16(af[t], bfr[u], acc[t][u], 0, 0, 0);
        __syncthreads();
    }

    #pragma unroll
    for (int t = 0; t < 2; ++t) {
        #pragma unroll
        for (int u = 0; u < 2; ++u) {
            int col = n0 + wn + u * 16 + cl;
            float bs = bias[col];
            #pragma unroll
            for (int i = 0; i < 4; ++i) {
                int row = m0 + wm + t * 16 + qd * 4 + i;
                float v = acc[t][u][i] + bs;
                if (mode == 0) {
                    Cb[(long)row * N + col] = __float2bfloat16(v);
                } else {
                    int b = row >> 10;
                    float g = gates[b * 2048 + gate_off + col];
                    Cf[(long)row * N + col] = resid[(long)row * N + col] + g * v;
                }
            }
        }
    }
}

// ---------------- fused MLP GEMM + h1*silu(h2), register-light ----------------
// R5 measured: 101us, 680 TF, VGPR 84, occ 27%. Keep.
__global__ __launch_bounds__(256) void gemm_mlp_kernel(
    const bf16* __restrict__ A, const bf16* __restrict__ Bt,
    const float* __restrict__ bias, bf16* __restrict__ ACT)
{
    __shared__ bf16 sA[128 * 32];
    __shared__ bf16 sB1[64 * 32];
    __shared__ bf16 sB2[64 * 32];
    const int tid = threadIdx.x;
    const int wave = tid >> 6, lane = tid & 63;
    const int num_pid_n = 64;            // 4096/64
    const int pid = blockIdx.x;
    const int group_size = 8 * num_pid_n;
    const int group_id = pid / group_size;
    const int pid_in = pid - group_id * group_size;
    const int pid_m = group_id * 8 + (pid_in & 7);
    const int pid_n = pid_in >> 3;
    const int m0 = pid_m * 128, n0 = pid_n * 64;
    const int wm = (wave & 1) * 64, wn = (wave >> 1) * 32;
    const int cl = lane & 15, qd = lane >> 4;
    const int K = 1024;

    f32x4 acc1[4][2] = {};
    f32x4 acc2[4][2] = {};

    const int c0 = wave * 128 + lane, c1 = c0 + 64;
    const int ra0 = c0 >> 2, sa0 = (c0 & 3) ^ ((c0 >> 3) & 3);
    const int ra1 = c1 >> 2, sa1 = (c1 & 3) ^ ((c1 >> 3) & 3);
    const int rb = tid >> 2, sb = (tid & 3) ^ ((tid >> 3) & 3);
    const bf16* gA0 = A + (long)(m0 + ra0) * K + sa0 * 8;
    const bf16* gA1 = A + (long)(m0 + ra1) * K + sa1 * 8;
    const bf16* gB1 = Bt + (long)(n0 + rb) * K + sb * 8;
    const bf16* gB2 = Bt + (long)(4096 + n0 + rb) * K + sb * 8;
    bf16* lA0 = &sA[wave * 1024];
    bf16* lA1 = &sA[wave * 1024 + 512];
    bf16* lB1 = &sB1[wave * 512];
    bf16* lB2 = &sB2[wave * 512];

    const int q8s = (qd ^ ((cl >> 1) & 3)) * 8;

    for (int kc = 0; kc < K; kc += 32) {
        gl_lds16(gA0 + kc, lA0);
        gl_lds16(gA1 + kc, lA1);
        gl_lds16(gB1 + kc, lB1);
        gl_lds16(gB2 + kc, lB2);
        __syncthreads();
        bf16x8 af[4], b1[2], b2[2];
        #pragma unroll
        for (int t = 0; t < 4; ++t)
            af[t] = *(const bf16x8*)&sA[(wm + cl + t * 16) * 32 + q8s];
        #pragma unroll
        for (int u = 0; u < 2; ++u) {
            b1[u] = *(const bf16x8*)&sB1[(wn + cl + u * 16) * 32 + q8s];
            b2[u] = *(const bf16x8*)&sB2[(wn + cl + u * 16) * 32 + q8s];
        }
        #pragma unroll
        for (int t = 0; t < 4; ++t)
            #pragma unroll
            for (int u = 0; u < 2; ++u) {
                acc1[t][u] = __builtin_amdgcn_mfma_f32_16x16x32_bf16(af[t], b1[u], acc1[t][u], 0, 0, 0);
                acc2[t][u] = __builtin_amdgcn_mfma_f32_16x16x32_bf16(af[t], b2[u], acc2[t][u], 0, 0, 0);
            }
        __syncthreads();
    }

    #pragma unroll
    for (int t = 0; t < 4; ++t) {
        #pragma unroll
        for (int u = 0; u < 2; ++u) {
            int col = n0 + wn + u * 16 + cl;
            float bs1 = bias[col];
            float bs2 = bias[4096 + col];
            #pragma unroll
            for (int i = 0; i < 4; ++i) {
                int row = m0 + wm + t * 16 + qd * 4 + i;
                float h1 = acc1[t][u][i] + bs1;
                float h2 = acc2[t][u][i] + bs2;
                float sg = 1.f / (1.f + __expf(-h2));
                ACT[(long)row * 4096 + col] = __float2bfloat16(h1 * h2 * sg);
            }
        }
    }
}

// ---------------- rope + per-head RMS norm; reformat q,k,v ----------------
__global__ __launch_bounds__(256) void ropenorm_kernel(
    const bf16* __restrict__ qkv, const float* __restrict__ nq_w, const float* __restrict__ nk_w,
    bf16* __restrict__ qh, bf16* __restrict__ kh, bf16* __restrict__ vt)
{
    int gid = blockIdx.x * 4 + (threadIdx.x >> 6);  // (b*S+s)*H + h
    int lane = threadIdx.x & 63;
    int b = gid >> 14, s = (gid >> 4) & (S_ - 1), h = gid & (H_ - 1);
    const long base = (long)(b * S_ + s) * 3072 + h * 64 + lane;
    float qv = __bfloat162float(qkv[base]);
    float kv = __bfloat162float(qkv[base + 1024]);
    float vv = __bfloat162float(qkv[base + 2048]);
    // rope
    int j = lane & 31;
    float inv = exp2f(-(float)j * (13.287712379549449f / 32.f)); // 10000^(-j/32)
    float ang = (float)s * inv;
    float sn, c;
    sincosf(ang, &sn, &c);
    float pq = __shfl_xor(qv, 32);
    float pk = __shfl_xor(kv, 32);
    float rq = (lane < 32) ? -pq : pq;
    float rk = (lane < 32) ? -pk : pk;
    float qr = qv * c + rq * sn;
    float kr = kv * c + rk * sn;
    // rms norm over 64 lanes
    float sq = qr * qr, sk = kr * kr;
    #pragma unroll
    for (int off = 32; off; off >>= 1) { sq += __shfl_xor(sq, off); sk += __shfl_xor(sk, off); }
    float nq = sqrtf(sq) * 0.125f;   // / sqrt(64)
    float nk = sqrtf(sk) * 0.125f;
    float qo = qr / (nq + 1e-6f) * nq_w[lane];
    float ko = kr / (nk + 1e-6f) * nk_w[lane];
    long hb = ((long)(b * H_ + h) * S_ + s) * 64 + lane;
    qh[hb] = __float2bfloat16(qo);
    kh[hb] = __float2bfloat16(ko);
    vt[((long)(b * H_ + h) * 64 + lane) * S_ + s] = __float2bfloat16(vv);
}

// ---------------- fused flash-style attention, fixed-shift softmax ------------
// Q,K rows are RMS-normalized (unit weights) -> ||q||=||k||=8, so by
// Cauchy-Schwarz scores = q.k/8 are in [-8, 8]. Softmax is shift-invariant:
// use fixed shift 8 instead of online running max. exp(s-8) in [e^-16, 1] --
// no overflow, and no m_i/rescale machinery (~50% of softmax VALU deleted).
__global__ __launch_bounds__(256) void attn_kernel(
    const bf16* __restrict__ qh, const bf16* __restrict__ kh, const bf16* __restrict__ vt,
    bf16* __restrict__ ao)
{
    const int bh = blockIdx.y;
    const int q0 = blockIdx.x * 64;
    const int tid = threadIdx.x, wave = tid >> 6, lane = tid & 63;
    const int cl = lane & 15, qd = lane >> 4;

    __shared__ bf16 sQ[64 * 72];
    __shared__ bf16 sK[64 * 72];
    __shared__ bf16 sV[64 * 72];
    __shared__ bf16 sP[4][16 * 72];

    {   // stage Q tile (64x64)
        const bf16* Qg = qh + (long)bh * S_ * 64 + (long)q0 * 64;
        int a = tid, b2 = tid + 256;
        *(uint4*)&sQ[(a >> 3) * 72 + (a & 7) * 8]  = *(const uint4*)&Qg[(a >> 3) * 64 + (a & 7) * 8];
        *(uint4*)&sQ[(b2 >> 3) * 72 + (b2 & 7) * 8] = *(const uint4*)&Qg[(b2 >> 3) * 64 + (b2 & 7) * 8];
    }

    float l_i[4] = {0.f, 0.f, 0.f, 0.f};
    f32x4 o_acc[4] = {};

    const bf16* Kg = kh + (long)bh * S_ * 64;
    const bf16* Vg = vt + (long)bh * 64 * S_;

    for (int kv0 = 0; kv0 < S_; kv0 += 64) {
        __syncthreads();
        {   // stage K tile [kv][d] and V^T tile [d][kv]
            int a = tid, b2 = tid + 256;
            *(uint4*)&sK[(a >> 3) * 72 + (a & 7) * 8]   = *(const uint4*)&Kg[((long)kv0 + (a >> 3)) * 64 + (a & 7) * 8];
            *(uint4*)&sK[(b2 >> 3) * 72 + (b2 & 7) * 8] = *(const uint4*)&Kg[((long)kv0 + (b2 >> 3)) * 64 + (b2 & 7) * 8];
            *(uint4*)&sV[(a >> 3) * 72 + (a & 7) * 8]   = *(const uint4*)&Vg[(long)(a >> 3) * S_ + kv0 + (a & 7) * 8];
            *(uint4*)&sV[(b2 >> 3) * 72 + (b2 & 7) * 8] = *(const uint4*)&Vg[(long)(b2 >> 3) * S_ + kv0 + (b2 & 7) * 8];
        }
        __syncthreads();

        // S = Q_wave (16 x 64) @ K_tile^T  -> 4 col-tiles of 16
        f32x4 sfr[4] = {};
        #pragma unroll
        for (int u = 0; u < 4; ++u) {
            #pragma unroll
            for (int ks = 0; ks < 2; ++ks) {
                bf16x8 aq = *(const bf16x8*)&sQ[(wave * 16 + cl) * 72 + ks * 32 + qd * 8];
                bf16x8 bk = *(const bf16x8*)&sK[(u * 16 + cl) * 72 + ks * 32 + qd * 8];
                sfr[u] = __builtin_amdgcn_mfma_f32_16x16x32_bf16(aq, bk, sfr[u], 0, 0, 0);
            }
        }

        // fixed-shift softmax: p = exp(s*0.125 - 8), accumulate l_i
        #pragma unroll
        for (int i = 0; i < 4; ++i) {
            float sum = 0.f;
            #pragma unroll
            for (int u = 0; u < 4; ++u) {
                float p = __expf(sfr[u][i] * 0.125f - 8.f);
                sum += p;
                sP[wave][(qd * 4 + i) * 72 + u * 16 + cl] = __float2bfloat16(p);
            }
            sum += __shfl_xor(sum, 1);
            sum += __shfl_xor(sum, 2);
            sum += __shfl_xor(sum, 4);
            sum += __shfl_xor(sum, 8);
            l_i[i] += sum;
        }

        // O += P (16 x 64kv) @ V (64kv x 64d); P read back in A-layout from LDS
        #pragma unroll
        for (int ks = 0; ks < 2; ++ks) {
            bf16x8 ap = *(const bf16x8*)&sP[wave][cl * 72 + ks * 32 + qd * 8];
            #pragma unroll
            for (int u = 0; u < 4; ++u) {
                bf16x8 bv = *(const bf16x8*)&sV[(u * 16 + cl) * 72 + ks * 32 + qd * 8];
                o_acc[u] = __builtin_amdgcn_mfma_f32_16x16x32_bf16(ap, bv, o_acc[u], 0, 0, 0);
            }
        }
    }

    // epilogue: ao[b, s, h*64+d]
    #pragma unroll
    for (int i = 0; i < 4; ++i) {
        float invl = 1.f / l_i[i];
        int row = q0 + wave * 16 + qd * 4 + i;
        #pragma unroll
        for (int u = 0; u < 4; ++u) {
            int d = u * 16 + cl;
            ao[((long)(bh >> 4) * S_ + row) * D_ + (bh & 15) * 64 + d] =
                __float2bfloat16(o_acc[u][i] * invl);
        }
    }
}

extern "C" void kernel_launch(void* const* d_in, const int* in_sizes, int n_in,
                              void* d_out, int out_size, void* d_ws, size_t ws_size,
                              hipStream_t stream) {
    const float* x       = (const float*)d_in[0];
    const float* emb     = (const float*)d_in[1];
    const float* ln1_w   = (const float*)d_in[2];
    const float* ln1_lW  = (const float*)d_in[3];
    const float* ln1_lb  = (const float*)d_in[4];
    const float* ln2_w   = (const float*)d_in[5];
    const float* ln2_lW  = (const float*)d_in[6];
    const float* ln2_lb  = (const float*)d_in[7];
    const float* qkv_W   = (const float*)d_in[8];
    const float* qkv_b   = (const float*)d_in[9];
    const float* proj_W  = (const float*)d_in[10];
    const float* proj_b  = (const float*)d_in[11];
    const float* nq_w    = (const float*)d_in[12];
    const float* nk_w    = (const float*)d_in[13];
    const float* mlp_W   = (const float*)d_in[14];
    const float* mlp_b   = (const float*)d_in[15];
    const float* out_W   = (const float*)d_in[16];
    const float* out_b   = (const float*)d_in[17];
    const float* gates_W = (const float*)d_in[18];
    const float* gates_b = (const float*)d_in[19];
    float* out = (float*)d_out;

    // workspace layout (all offsets 256B aligned)
    char* p = (char*)d_ws;
    if (ws_size < 159481856UL) return;  // loud failure rather than OOB corruption
    bf16* WT_QKV  = (bf16*)p;  p += 6291456;   // [3072][1024]
    bf16* WT_PROJ = (bf16*)p;  p += 2097152;   // [1024][1024]
    bf16* WT_MLP  = (bf16*)p;  p += 16777216;  // [8192][1024]
    bf16* WT_OUT  = (bf16*)p;  p += 8388608;   // [1024][4096]
    float* G      = (float*)p; p += 32768;     // [4][2048]
    float* SSb    = (float*)p; p += 32768;
    float* SS2b   = (float*)p; p += 32768;
    float* X1     = (float*)p; p += 16777216;  // f32 [4096][1024]
    bf16* XN2     = (bf16*)p;  p += 8388608;
    bf16* ACT     = (bf16*)p;  p += 33554432;  // [4096][4096]
    char* REG = p;                              // reused region
    bf16* XN   = (bf16*)(REG);
    bf16* QKV  = (bf16*)(REG + 8388608);       // [4096][3072]
    bf16* QH   = (bf16*)(REG + 33554432);      // [B,H,S,HD]
    bf16* KH   = (bf16*)(REG + 41943040);
    bf16* VT   = (bf16*)(REG + 50331648);      // [B,H,HD,S]
    bf16* AO   = (bf16*)(REG + 58720256);      // [4096][1024]

    dim3 blk(256);
    // zero G/SSb/SS2b (96 KB) for embgemm's atomicAdd k-split
    hipMemsetAsync(G, 0, 98304, stream);
    transpose_kernel<<<dim3(96, 32),  blk, 0, stream>>>(qkv_W,  WT_QKV, 1024, 3072);
    transpose_kernel<<<dim3(32, 32),  blk, 0, stream>>>(proj_W, WT_PROJ, 1024, 1024);
    transpose_kernel<<<dim3(256, 32), blk, 0, stream>>>(mlp_W,  WT_MLP, 1024, 8192);
    transpose_kernel<<<dim3(32, 128), blk, 0, stream>>>(out_W,  WT_OUT, 4096, 1024);
    embgemm_kernel<<<dim3(24, 4, 4), blk, 0, stream>>>(emb, gates_W, gates_b, ln1_lW, ln1_lb,
                                                       ln2_lW, ln2_lb, G, SSb, SS2b);
    rmsmod_kernel<<<dim3(4096), blk, 0, stream>>>(x, ln1_w, SSb, XN);
    gemm_kernel<<<dim3(768), blk, 0, stream>>>(XN, WT_QKV, qkv_b, QKV, nullptr,
                                               nullptr, nullptr, 0, 4096, 3072, 1024, 0);
    ropenorm_kernel<<<dim3(16384), blk, 0, stream>>>(QKV, nq_w, nk_w, QH, KH, VT);
    attn_kernel<<<dim3(16, 64), blk, 0, stream>>>(QH, KH, VT, AO);
    gemm64_kernel<<<dim3(1024), blk, 0, stream>>>(AO, WT_PROJ, proj_b, nullptr, X1,
                                                  x, G, 0, 4096, 1024, 1024, 1);
    rmsmod_kernel<<<dim3(4096), blk, 0, stream>>>(X1, ln2_w, SS2b, XN2);
    gemm_mlp_kernel<<<dim3(2048), blk, 0, stream>>>(XN2, WT_MLP, mlp_b, ACT);
    gemm64_kernel<<<dim3(1024), blk, 0, stream>>>(ACT, WT_OUT, out_b, nullptr, out,
                                                  X1, G, 1024, 4096, 1024, 4096, 1);
}